// Round 8
// baseline (94.438 us; speedup 1.0000x reference)
//
#include <hip/hip_runtime.h>
#include <hip/hip_bf16.h>

typedef __bf16 bf16x8 __attribute__((ext_vector_type(8)));
typedef __bf16 bf16x4 __attribute__((ext_vector_type(4)));
typedef float  f32x16 __attribute__((ext_vector_type(16)));
typedef float  f32x4  __attribute__((ext_vector_type(4)));

#define HD     2048   // H*D floats per token row
#define DH     128
#define KVT    128    // kv tile
#define NCH    8      // tiles per split half (1024/128)
#define NSPLIT 2
#define NROWS  32768  // Lq*H
#define TILE_ELEMS 16384   // 128x128 bf16
#define TILE_BYTES 32768

// global_load_lds: LDS dest = wave-uniform base + lane*16 (HW); global src per-lane.
__device__ __forceinline__ void glds16(const void* g, void* l) {
    typedef const __attribute__((address_space(1))) void g_as_t;
    typedef __attribute__((address_space(3))) void l_as_t;
    __builtin_amdgcn_global_load_lds((g_as_t*)g, (l_as_t*)l, 16, 0, 0);
}

// ---------------------------------------------------------------------------
// Prepass 1: K[kv][h][d] fp32 -> wsK[h][T][r=kv&127][granule-swizzled d] bf16.
// Swizzle: 16B granule index c8 (0..15) stored at c8 ^ (r&15). XOR involution;
// main kernel reads with the same XOR (guide rule 21: pre-swizzled source +
// linear glds + swizzled read).  2048 blocks x 256 thr; 32B read/thread.
// ---------------------------------------------------------------------------
__global__ __launch_bounds__(256, 8)
void prep_k(const float* __restrict__ Kg, __bf16* __restrict__ wsK)
{
    const int kv = blockIdx.x;
    const int t  = threadIdx.x;
    const int h  = t >> 4, c8 = t & 15;
    const float* src = Kg + (size_t)kv * HD + h * DH + c8 * 8;
    f32x4 a = *(const f32x4*)(src);
    f32x4 b = *(const f32x4*)(src + 4);
    bf16x8 o;
    o[0]=(__bf16)a[0]; o[1]=(__bf16)a[1]; o[2]=(__bf16)a[2]; o[3]=(__bf16)a[3];
    o[4]=(__bf16)b[0]; o[5]=(__bf16)b[1]; o[6]=(__bf16)b[2]; o[7]=(__bf16)b[3];
    __bf16* dst = wsK + ((size_t)(h * 16 + (kv >> 7)) << 14)
                      + (kv & 127) * 128 + ((c8 ^ (kv & 15)) << 3);
    *(bf16x8*)dst = o;
}

// ---------------------------------------------------------------------------
// Prepass 2: V[kv][h][dv] fp32 -> wsV[h][T][dv][kv-granule-swizzled] bf16.
// 32x32 LDS transpose tiles (R6-verified shape). Swizzle: kv-granule kg
// (0..15 within 128-kv row) stored at kg ^ (dv&15).
// grid b = h*256 + kvb*4 + dvb (4096 blocks).
// ---------------------------------------------------------------------------
__global__ __launch_bounds__(256, 4)
void prep_vt(const float* __restrict__ Vg, __bf16* __restrict__ wsV)
{
    __shared__ float tile[32][33];
    const int b = blockIdx.x;
    const int dvb = b & 3, kvb = (b >> 2) & 63, h = b >> 8;
    const int t = threadIdx.x;
    {
        const int kvl = t >> 3, dv4 = (t & 7) * 4;
        f32x4 v = *(const f32x4*)(Vg + (size_t)(kvb * 32 + kvl) * HD + h * DH + dvb * 32 + dv4);
        tile[kvl][dv4 + 0] = v[0]; tile[kvl][dv4 + 1] = v[1];
        tile[kvl][dv4 + 2] = v[2]; tile[kvl][dv4 + 3] = v[3];
    }
    __syncthreads();
    {
        const int dvl = t >> 3, kv4 = (t & 7) * 4;
        const int dv = dvb * 32 + dvl;
        const int T  = kvb >> 2;
        const int kvloc = (kvb & 3) * 32 + kv4;      // 0..127, 4 elems same granule
        const int kg = kvloc >> 3;
        bf16x4 o;
        o[0] = (__bf16)tile[kv4 + 0][dvl]; o[1] = (__bf16)tile[kv4 + 1][dvl];
        o[2] = (__bf16)tile[kv4 + 2][dvl]; o[3] = (__bf16)tile[kv4 + 3][dvl];
        __bf16* dst = wsV + ((size_t)(h * 16 + T) << 14)
                          + dv * 128 + (((kg ^ (dv & 15)) << 3) + (kvloc & 7));
        *(bf16x4*)dst = o;
    }
}

// ---------------------------------------------------------------------------
// Main attention: 512 thr = 8 warps x 32 q = 256 q/block; KVT=128, 8 iters.
// Staging = pure linear 32KB glds copy per tile (no regs, no cvt, no ds_write).
// One vmcnt(0)+lgkmcnt(0)+barrier per iter; glds for t+1 issued at top of
// iter t -> full-iteration cover (m97 structure). 16-deep XOR swizzle makes
// K b128 and V b64 reads conflict-free. Grid 256 = 8 qblk x (16h x 2sp);
// grp%8 = XCD keeps each (h,sp) 512KB bf16 KV slice in one XCD's L2.
// ---------------------------------------------------------------------------
__global__ __launch_bounds__(512, 2)
void fmha_main(const float* __restrict__ Qg,
               const __bf16* __restrict__ wsK, const __bf16* __restrict__ wsV,
               float* __restrict__ wsO, float* __restrict__ wsML)
{
    __shared__ __align__(16) __bf16 klds[2][TILE_ELEMS];
    __shared__ __align__(16) __bf16 vlds[2][TILE_ELEMS];

    const int tid  = threadIdx.x;
    const int lane = tid & 63;
    const int wrp  = tid >> 6;
    const int g    = lane >> 5;
    const int l31  = lane & 31;

    const int b    = blockIdx.x;
    const int grp  = b & 31;
    const int qblk = b >> 5;
    const int h    = grp >> 1;
    const int sp   = grp & 1;
    const int T0   = sp * NCH;

    const float qscale = 1.4426950408889634f * 0.08838834764831845f; // log2(e)/sqrt(128)
    const int q = qblk * 256 + wrp * 32 + l31;

    // ---- Q fragments (B-operand of QK^T): lane=q-row, d = j*16 + 8g + e
    bf16x8 qf[8];
    {
        const float* qrow = Qg + (size_t)q * HD + h * DH;
        #pragma unroll
        for (int j = 0; j < 8; ++j) {
            f32x4 a = *(const f32x4*)(qrow + j * 16 + 8 * g);
            f32x4 c = *(const f32x4*)(qrow + j * 16 + 8 * g + 4);
            bf16x8 f;
            f[0] = (__bf16)(a[0] * qscale); f[1] = (__bf16)(a[1] * qscale);
            f[2] = (__bf16)(a[2] * qscale); f[3] = (__bf16)(a[3] * qscale);
            f[4] = (__bf16)(c[0] * qscale); f[5] = (__bf16)(c[1] * qscale);
            f[6] = (__bf16)(c[2] * qscale); f[7] = (__bf16)(c[3] * qscale);
            qf[j] = f;
        }
    }

    // ---- staging: wave w copies bytes [r*8192 + w*1024, +1024) of each tile
    const int woff = wrp * 1024;    // wave-uniform LDS/global chunk base
    const int lb16 = lane * 16;     // global-side lane offset (LDS side is HW-added)

    auto stage = [&](int T, int buf) {
        const char* kt = (const char*)wsK + (size_t)(h * 16 + T) * TILE_BYTES + woff + lb16;
        const char* vt = (const char*)wsV + (size_t)(h * 16 + T) * TILE_BYTES + woff + lb16;
        char* kl = (char*)&klds[buf][0] + woff;
        char* vl = (char*)&vlds[buf][0] + woff;
        #pragma unroll
        for (int r = 0; r < 4; ++r) {
            glds16(kt + r * 8192, kl + r * 8192);
            glds16(vt + r * 8192, vl + r * 8192);
        }
    };

    auto sync_all = []() {
        asm volatile("s_waitcnt vmcnt(0) lgkmcnt(0)" ::: "memory");
        __builtin_amdgcn_s_barrier();
    };

    float mrun = -1e30f, lrun = 0.0f;
    f32x16 o0, o1, o2, o3;
    #pragma unroll
    for (int r = 0; r < 16; ++r) { o0[r] = 0.f; o1[r] = 0.f; o2[r] = 0.f; o3[r] = 0.f; }

    stage(T0, 0);
    sync_all();

    const int ksw = l31 & 15;   // row&15 == l31&15 for all row groups (+32k)

    #pragma unroll 2
    for (int tt = 0; tt < NCH; ++tt) {
        const int cur = tt & 1;
        if (tt + 1 < NCH) stage(T0 + tt + 1, cur ^ 1);   // issue-early, full-iter cover

        // ---- QK^T (swapped): S^T[kv][q], 4 independent 32-kv chains
        f32x16 s0, s1, s2, s3;
        #pragma unroll
        for (int r = 0; r < 16; ++r) { s0[r]=0.f; s1[r]=0.f; s2[r]=0.f; s3[r]=0.f; }
        __builtin_amdgcn_s_setprio(1);
        #pragma unroll
        for (int j = 0; j < 8; ++j) {
            const int gcol = ((2 * j + g) ^ ksw) << 3;
            bf16x8 k0 = *(const bf16x8*)&klds[cur][ l31        * 128 + gcol];
            s0 = __builtin_amdgcn_mfma_f32_32x32x16_bf16(k0, qf[j], s0, 0, 0, 0);
            bf16x8 k1 = *(const bf16x8*)&klds[cur][(32 + l31)  * 128 + gcol];
            s1 = __builtin_amdgcn_mfma_f32_32x32x16_bf16(k1, qf[j], s1, 0, 0, 0);
            bf16x8 k2 = *(const bf16x8*)&klds[cur][(64 + l31)  * 128 + gcol];
            s2 = __builtin_amdgcn_mfma_f32_32x32x16_bf16(k2, qf[j], s2, 0, 0, 0);
            bf16x8 k3 = *(const bf16x8*)&klds[cur][(96 + l31)  * 128 + gcol];
            s3 = __builtin_amdgcn_mfma_f32_32x32x16_bf16(k3, qf[j], s3, 0, 0, 0);
        }
        __builtin_amdgcn_s_setprio(0);

        // ---- online softmax over 64 slots (128 kv with partner lane^32)
        float m16[8];
        #pragma unroll
        for (int r = 0; r < 8; ++r)
            m16[r] = fmaxf(fmaxf(fmaxf(s0[r], s0[r+8]), fmaxf(s1[r], s1[r+8])),
                           fmaxf(fmaxf(s2[r], s2[r+8]), fmaxf(s3[r], s3[r+8])));
        float tmax = fmaxf(fmaxf(fmaxf(m16[0], m16[4]), fmaxf(m16[1], m16[5])),
                           fmaxf(fmaxf(m16[2], m16[6]), fmaxf(m16[3], m16[7])));
        tmax = fmaxf(tmax, __shfl_xor(tmax, 32, 64));

        if (__any(tmax > mrun + 8.0f)) {   // T13 defer-max (base-2, P <= 2^8)
            const float mnew  = fmaxf(mrun, tmax);
            const float alpha = __builtin_amdgcn_exp2f(mrun - mnew);
            lrun *= alpha;
            #pragma unroll
            for (int r = 0; r < 16; ++r) { o0[r]*=alpha; o1[r]*=alpha; o2[r]*=alpha; o3[r]*=alpha; }
            mrun = mnew;
        }

        #pragma unroll
        for (int r = 0; r < 16; ++r) {   // exp in place: s becomes P
            s0[r] = __builtin_amdgcn_exp2f(s0[r] - mrun);
            s1[r] = __builtin_amdgcn_exp2f(s1[r] - mrun);
            s2[r] = __builtin_amdgcn_exp2f(s2[r] - mrun);
            s3[r] = __builtin_amdgcn_exp2f(s3[r] - mrun);
        }
        float ps = 0.f;
        #pragma unroll
        for (int r = 0; r < 16; ++r) ps += (s0[r] + s1[r]) + (s2[r] + s3[r]);
        lrun += ps;

        // P -> bf16 fragments (S^T C/D reg order == PV B-slot order, verified)
        bf16x8 pf0, pf1, pf2, pf3, pf4, pf5, pf6, pf7;
        #pragma unroll
        for (int e = 0; e < 8; ++e) {
            pf0[e] = (__bf16)s0[e]; pf1[e] = (__bf16)s0[8 + e];
            pf2[e] = (__bf16)s1[e]; pf3[e] = (__bf16)s1[8 + e];
            pf4[e] = (__bf16)s2[e]; pf5[e] = (__bf16)s2[8 + e];
            pf6[e] = (__bf16)s3[e]; pf7[e] = (__bf16)s3[8 + e];
        }

        // ---- PV: O^T[dv][q] += V^T[dv][kv] * P^T[kv][q]
        __builtin_amdgcn_s_setprio(1);
        #pragma unroll
        for (int bb = 0; bb < 4; ++bb) {
            const __bf16* vb = &vlds[cur][(bb * 32 + l31) * 128];
            f32x16& oo = (bb == 0) ? o0 : (bb == 1) ? o1 : (bb == 2) ? o2 : o3;
            #define PVSTEP(m, pf)                                                 \
            {                                                                     \
                bf16x4 a0 = *(const bf16x4*)(vb + (((2*(m))   ^ ksw) << 3) + 4*g);\
                bf16x4 a1 = *(const bf16x4*)(vb + (((2*(m)+1) ^ ksw) << 3) + 4*g);\
                bf16x8 va;                                                        \
                va[0]=a0[0]; va[1]=a0[1]; va[2]=a0[2]; va[3]=a0[3];               \
                va[4]=a1[0]; va[5]=a1[1]; va[6]=a1[2]; va[7]=a1[3];               \
                oo = __builtin_amdgcn_mfma_f32_32x32x16_bf16(va, pf, oo, 0, 0, 0);\
            }
            PVSTEP(0, pf0) PVSTEP(1, pf1) PVSTEP(2, pf2) PVSTEP(3, pf3)
            PVSTEP(4, pf4) PVSTEP(5, pf5) PVSTEP(6, pf6) PVSTEP(7, pf7)
            #undef PVSTEP
        }
        __builtin_amdgcn_s_setprio(0);

        if (tt + 1 < NCH) sync_all();
    }

    // ---- epilogue: unnormalized O' + (m,l)
    const float ltot  = lrun + __shfl_xor(lrun, 32, 64);
    const int   rowid = q * 16 + h;

    float* orow = wsO + ((size_t)sp * NROWS + rowid) * 128;
    #pragma unroll
    for (int bb = 0; bb < 4; ++bb) {
        const f32x16& oo = (bb == 0) ? o0 : (bb == 1) ? o1 : (bb == 2) ? o2 : o3;
        #pragma unroll
        for (int jj = 0; jj < 4; ++jj) {
            f32x4 v;
            v[0] = oo[4*jj+0]; v[1] = oo[4*jj+1]; v[2] = oo[4*jj+2]; v[3] = oo[4*jj+3];
            *(f32x4*)(orow + bb * 32 + 8 * jj + 4 * g) = v;
        }
    }
    if (lane < 32) {
        float* ml = wsML + ((size_t)sp * NROWS + rowid) * 2;
        ml[0] = mrun;
        ml[1] = ltot;
    }
}

// ---------------------------------------------------------------------------
// Combine: O[row] = sum_s 2^(m_s - M) * O'_s[row] / L.
// ---------------------------------------------------------------------------
__global__ __launch_bounds__(256, 4)
void fmha_combine(const float* __restrict__ wsO, const float* __restrict__ wsML,
                  float* __restrict__ Og)
{
    const int tid   = threadIdx.x;
    const int rowid = blockIdx.x * 8 + (tid >> 5);
    const int c     = (tid & 31) * 4;

    float m[NSPLIT], l[NSPLIT];
    float M = -1e30f;
    #pragma unroll
    for (int s = 0; s < NSPLIT; ++s) {
        const float* ml = wsML + ((size_t)s * NROWS + rowid) * 2;
        m[s] = ml[0]; l[s] = ml[1];
        M = fmaxf(M, m[s]);
    }
    float L = 0.f, w[NSPLIT];
    #pragma unroll
    for (int s = 0; s < NSPLIT; ++s) {
        w[s] = __builtin_amdgcn_exp2f(m[s] - M);
        L += l[s] * w[s];
    }
    const float inv = 1.0f / L;

    f32x4 acc; acc[0]=0.f; acc[1]=0.f; acc[2]=0.f; acc[3]=0.f;
    #pragma unroll
    for (int s = 0; s < NSPLIT; ++s) {
        f32x4 v = *(const f32x4*)(wsO + ((size_t)s * NROWS + rowid) * 128 + c);
        acc[0] += v[0] * w[s]; acc[1] += v[1] * w[s];
        acc[2] += v[2] * w[s]; acc[3] += v[3] * w[s];
    }
    f32x4 r;
    r[0] = acc[0]*inv; r[1] = acc[1]*inv; r[2] = acc[2]*inv; r[3] = acc[3]*inv;
    *(f32x4*)(Og + (size_t)rowid * 128 + c) = r;
}

// ---------------------------------------------------------------------------
// Fallback (ws too small — not expected): R1-style single-pass kernel.
// ---------------------------------------------------------------------------
__global__ __launch_bounds__(256, 2)
void fmha_fb(const float* __restrict__ Qg, const float* __restrict__ Kg,
             const float* __restrict__ Vg, float* __restrict__ Og)
{
    __shared__ __align__(16) __bf16 klds[2][32 * 128];
    __shared__ __align__(16) __bf16 vtlds[2][DH * 36];

    const int tid  = threadIdx.x;
    const int lane = tid & 63;
    const int wrp  = tid >> 6;
    const int g    = lane >> 5;
    const int l31  = lane & 31;

    const int b    = blockIdx.x;
    const int h    = 2 * (b & 7) + ((b >> 3) >> 4);
    const int qblk = (b >> 3) & 15;

    const float qscale = 1.4426950408889634f * 0.08838834764831845f;
    const int q = qblk * 128 + wrp * 32 + l31;

    bf16x8 qf[8];
    {
        const float* qrow = Qg + (size_t)q * HD + h * DH;
        #pragma unroll
        for (int db = 0; db < 8; ++db) {
            f32x4 a = *(const f32x4*)(qrow + db * 16 + 8 * g);
            f32x4 c = *(const f32x4*)(qrow + db * 16 + 8 * g + 4);
            bf16x8 f;
            f[0] = (__bf16)(a[0] * qscale); f[1] = (__bf16)(a[1] * qscale);
            f[2] = (__bf16)(a[2] * qscale); f[3] = (__bf16)(a[3] * qscale);
            f[4] = (__bf16)(c[0] * qscale); f[5] = (__bf16)(c[1] * qscale);
            f[6] = (__bf16)(c[2] * qscale); f[7] = (__bf16)(c[3] * qscale);
            qf[db] = f;
        }
    }

    const int krow = tid >> 3, kc = tid & 7;
    const int vkv  = tid & 31, vdv0 = (tid >> 5) * 16;
    const float* kbase = Kg + (size_t)h * DH;
    const float* vbase = Vg + (size_t)h * DH;

    f32x4 kreg0, kreg1, kreg2, kreg3, vreg0, vreg1, vreg2, vreg3;

    auto stage_load = [&](int t) {
        const float* kp = kbase + (size_t)(t * 32 + krow) * HD + kc * 8;
        kreg0 = *(const f32x4*)(kp);
        kreg1 = *(const f32x4*)(kp + 4);
        kreg2 = *(const f32x4*)(kp + 64);
        kreg3 = *(const f32x4*)(kp + 68);
        const float* vp = vbase + (size_t)(t * 32 + vkv) * HD + vdv0;
        vreg0 = *(const f32x4*)(vp);
        vreg1 = *(const f32x4*)(vp + 4);
        vreg2 = *(const f32x4*)(vp + 8);
        vreg3 = *(const f32x4*)(vp + 12);
    };

    auto stage_write = [&](int buf) {
        bf16x8 k0, k1;
        k0[0]=(__bf16)kreg0[0]; k0[1]=(__bf16)kreg0[1]; k0[2]=(__bf16)kreg0[2]; k0[3]=(__bf16)kreg0[3];
        k0[4]=(__bf16)kreg1[0]; k0[5]=(__bf16)kreg1[1]; k0[6]=(__bf16)kreg1[2]; k0[7]=(__bf16)kreg1[3];
        k1[0]=(__bf16)kreg2[0]; k1[1]=(__bf16)kreg2[1]; k1[2]=(__bf16)kreg2[2]; k1[3]=(__bf16)kreg2[3];
        k1[4]=(__bf16)kreg3[0]; k1[5]=(__bf16)kreg3[1]; k1[6]=(__bf16)kreg3[2]; k1[7]=(__bf16)kreg3[3];
        const int swz = (krow & 7) << 3;
        *(bf16x8*)&klds[buf][krow * 128 + ((kc * 8) ^ swz)]      = k0;
        *(bf16x8*)&klds[buf][krow * 128 + ((kc * 8 + 64) ^ swz)] = k1;
        #pragma unroll
        for (int jj = 0; jj < 4; ++jj) {
            f32x4 vv = (jj == 0) ? vreg0 : (jj == 1) ? vreg1 : (jj == 2) ? vreg2 : vreg3;
            #pragma unroll
            for (int e = 0; e < 4; ++e)
                vtlds[buf][(vdv0 + jj * 4 + e) * 36 + vkv] = (__bf16)vv[e];
        }
    };

    float mrun = -1e30f, lrun = 0.0f;
    f32x16 o0, o1, o2, o3;
    #pragma unroll
    for (int r = 0; r < 16; ++r) { o0[r] = 0.f; o1[r] = 0.f; o2[r] = 0.f; o3[r] = 0.f; }

    stage_load(0);
    stage_write(0);

    for (int tt = 0; tt < 64; ++tt) {
        const int cur = tt & 1;
        if (tt + 1 < 64) stage_load(tt + 1);
        __syncthreads();

        f32x16 sa, sb;
        #pragma unroll
        for (int r = 0; r < 16; ++r) { sa[r] = 0.f; sb[r] = 0.f; }
        const int kswz = (l31 & 7) << 3;
        #pragma unroll
        for (int db = 0; db < 4; ++db) {
            bf16x8 kfa = *(const bf16x8*)&klds[cur][l31 * 128 + (((2*db)   * 16 + g * 8) ^ kswz)];
            sa = __builtin_amdgcn_mfma_f32_32x32x16_bf16(kfa, qf[2*db],   sa, 0, 0, 0);
            bf16x8 kfb = *(const bf16x8*)&klds[cur][l31 * 128 + (((2*db+1) * 16 + g * 8) ^ kswz)];
            sb = __builtin_amdgcn_mfma_f32_32x32x16_bf16(kfb, qf[2*db+1], sb, 0, 0, 0);
        }
        f32x16 s;
        #pragma unroll
        for (int r = 0; r < 16; ++r) s[r] = sa[r] + sb[r];

        float m8[8];
        #pragma unroll
        for (int r = 0; r < 8; ++r) m8[r] = fmaxf(s[r], s[r + 8]);
        float tmax = fmaxf(fmaxf(fmaxf(m8[0], m8[4]), fmaxf(m8[1], m8[5])),
                           fmaxf(fmaxf(m8[2], m8[6]), fmaxf(m8[3], m8[7])));
        tmax = fmaxf(tmax, __shfl_xor(tmax, 32, 64));

        if (__any(tmax > mrun + 8.0f)) {
            const float mnew  = fmaxf(mrun, tmax);
            const float alpha = __builtin_amdgcn_exp2f(mrun - mnew);
            lrun *= alpha;
            #pragma unroll
            for (int r = 0; r < 16; ++r) { o0[r] *= alpha; o1[r] *= alpha; o2[r] *= alpha; o3[r] *= alpha; }
            mrun = mnew;
        }

        float p[16];
        #pragma unroll
        for (int r = 0; r < 16; ++r) p[r] = __builtin_amdgcn_exp2f(s[r] - mrun);
        float ps0 = 0, ps1 = 0, ps2 = 0, ps3 = 0;
        #pragma unroll
        for (int r = 0; r < 4; ++r) { ps0 += p[r]; ps1 += p[r+4]; ps2 += p[r+8]; ps3 += p[r+12]; }
        lrun += ((ps0 + ps1) + (ps2 + ps3));

        bf16x8 pf0, pf1;
        #pragma unroll
        for (int e = 0; e < 8; ++e) { pf0[e] = (__bf16)p[e]; pf1[e] = (__bf16)p[8 + e]; }

        #pragma unroll
        for (int bb = 0; bb < 4; ++bb) {
            const __bf16* vb = &vtlds[cur][(bb * 32 + l31) * 36];
            bf16x4 a0 = *(const bf16x4*)(vb + 4 * g);
            bf16x4 a1 = *(const bf16x4*)(vb + 8 + 4 * g);
            bf16x8 va;
            va[0]=a0[0]; va[1]=a0[1]; va[2]=a0[2]; va[3]=a0[3];
            va[4]=a1[0]; va[5]=a1[1]; va[6]=a1[2]; va[7]=a1[3];
            f32x16& oo = (bb == 0) ? o0 : (bb == 1) ? o1 : (bb == 2) ? o2 : o3;
            oo = __builtin_amdgcn_mfma_f32_32x32x16_bf16(va, pf0, oo, 0, 0, 0);
            bf16x4 b0 = *(const bf16x4*)(vb + 16 + 4 * g);
            bf16x4 b1 = *(const bf16x4*)(vb + 24 + 4 * g);
            va[0]=b0[0]; va[1]=b0[1]; va[2]=b0[2]; va[3]=b0[3];
            va[4]=b1[0]; va[5]=b1[1]; va[6]=b1[2]; va[7]=b1[3];
            oo = __builtin_amdgcn_mfma_f32_32x32x16_bf16(va, pf1, oo, 0, 0, 0);
        }

        if (tt + 1 < 64) stage_write(cur ^ 1);
    }

    const float ltot = lrun + __shfl_xor(lrun, 32, 64);
    const float inv  = 1.0f / ltot;
    float* orow = Og + ((size_t)q * 16 + h) * 128;
    #pragma unroll
    for (int bb = 0; bb < 4; ++bb) {
        const f32x16& oo = (bb == 0) ? o0 : (bb == 1) ? o1 : (bb == 2) ? o2 : o3;
        #pragma unroll
        for (int jj = 0; jj < 4; ++jj) {
            f32x4 v;
            v[0] = oo[4*jj+0] * inv; v[1] = oo[4*jj+1] * inv;
            v[2] = oo[4*jj+2] * inv; v[3] = oo[4*jj+3] * inv;
            *(f32x4*)(orow + bb * 32 + 8 * jj + 4 * g) = v;
        }
    }
}

extern "C" void kernel_launch(void* const* d_in, const int* in_sizes, int n_in,
                              void* d_out, int out_size, void* d_ws, size_t ws_size,
                              hipStream_t stream) {
    const float* Q = (const float*)d_in[0];
    const float* K = (const float*)d_in[1];
    const float* V = (const float*)d_in[2];
    float* O = (float*)d_out;

    const size_t kv_bytes = (size_t)256 * TILE_BYTES;           // 8 MB each (16h x 16T)
    const size_t needO  = (size_t)NSPLIT * NROWS * 128;         // floats (32 MB)
    const size_t needML = (size_t)NSPLIT * NROWS * 2;           // floats
    const size_t need_bytes = 2 * kv_bytes + (needO + needML) * sizeof(float);

    if (ws_size >= need_bytes) {
        __bf16* wsK = (__bf16*)d_ws;
        __bf16* wsV = (__bf16*)((char*)d_ws + kv_bytes);
        float*  wsO = (float*)((char*)d_ws + 2 * kv_bytes);
        float*  wsML = wsO + needO;
        hipLaunchKernelGGL(prep_k,  dim3(2048), dim3(256), 0, stream, K, wsK);
        hipLaunchKernelGGL(prep_vt, dim3(4096), dim3(256), 0, stream, V, wsV);
        hipLaunchKernelGGL(fmha_main, dim3(256), dim3(512), 0, stream,
                           Q, wsK, wsV, wsO, wsML);
        hipLaunchKernelGGL(fmha_combine, dim3(NROWS / 8), dim3(256), 0, stream,
                           wsO, wsML, O);
    } else {
        hipLaunchKernelGGL(fmha_fb, dim3(256), dim3(256), 0, stream, Q, K, V, O);
    }
}